// Round 1
// baseline (990.528 us; speedup 1.0000x reference)
//
#include <hip/hip_runtime.h>

#define D 128
#define ALPHA 0.2f

// ---- order-preserving float<->uint encoding for atomicMax on float ----
__device__ __forceinline__ unsigned enc_f32(float f) {
    unsigned u = __float_as_uint(f);
    return (u & 0x80000000u) ? ~u : (u | 0x80000000u);
}
__device__ __forceinline__ float dec_f32(unsigned k) {
    return (k & 0x80000000u) ? __uint_as_float(k ^ 0x80000000u)
                             : __uint_as_float(~k);
}

// u1[i] = sum_j W_map[i][j]*w1[j]; u2[i] likewise with w2. One block of 128.
__global__ void k_compute_u(const float* __restrict__ Wmap,
                            const float* __restrict__ w1,
                            const float* __restrict__ w2,
                            float* __restrict__ u) {
    int i = threadIdx.x;
    float s1 = 0.f, s2 = 0.f;
    for (int j = 0; j < D; ++j) {
        float w = Wmap[i * D + j];
        s1 += w * w1[j];
        s2 += w * w2[j];
    }
    u[i] = s1;
    u[D + i] = s2;
}

// out = bias; mkey = 0; denom = 0
__global__ void k_init(const float* __restrict__ bias, float* __restrict__ out,
                       unsigned* __restrict__ mkey, float* __restrict__ denom,
                       int n) {
    int idx = blockIdx.x * blockDim.x + threadIdx.x;
    if (idx < n * D) out[idx] = bias[idx];
    if (idx < n) { mkey[idx] = 0u; denom[idx] = 0.f; }
}

// one wave per node: sa1[i] = x[i].u1 + b1, sa2[i] = x[i].u2 + b2
__global__ __launch_bounds__(256) void k_scores(
        const float* __restrict__ x, const float* __restrict__ u,
        const float* __restrict__ b1, const float* __restrict__ b2,
        float* __restrict__ sa1, float* __restrict__ sa2, int n) {
    int lane = threadIdx.x & 63;
    int node = blockIdx.x * 4 + (threadIdx.x >> 6);
    if (node >= n) return;
    float u1a = u[lane], u1b = u[64 + lane];
    float u2a = u[D + lane], u2b = u[D + 64 + lane];
    const float* xr = x + (size_t)node * D;
    float xa = xr[lane], xb = xr[64 + lane];
    float s1 = xa * u1a + xb * u1b;
    float s2 = xa * u2a + xb * u2b;
    #pragma unroll
    for (int off = 32; off > 0; off >>= 1) {
        s1 += __shfl_xor(s1, off);
        s2 += __shfl_xor(s2, off);
    }
    if (lane == 0) { sa1[node] = s1 + b1[0]; sa2[node] = s2 + b2[0]; }
}

// value = x @ kernel   ([n,128] @ [128,128])
// 64 rows per block; x tile staged transposed in LDS (padded stride 65);
// K columns read from global (64KB, L2-resident, coalesced across lanes).
#define GR 64
__global__ __launch_bounds__(256) void k_value_gemm(
        const float* __restrict__ x, const float* __restrict__ kern,
        float* __restrict__ value, int n) {
    __shared__ float Xt[D * (GR + 1)];
    int t = threadIdx.x;
    int rowbase = blockIdx.x * GR;
    int nrows = min(GR, n - rowbase);
    for (int i = t; i < nrows * D; i += 256) {
        int r = i >> 7, k = i & (D - 1);
        Xt[k * (GR + 1) + r] = x[(size_t)(rowbase + r) * D + k];
    }
    __syncthreads();
    int c = t & 127;
    int r0 = (t >> 7) * (GR / 2);
    float acc[GR / 2];
    #pragma unroll
    for (int j = 0; j < GR / 2; ++j) acc[j] = 0.f;
    for (int k = 0; k < D; ++k) {
        float kc = kern[k * D + c];
        #pragma unroll
        for (int j = 0; j < GR / 2; ++j)
            acc[j] += Xt[k * (GR + 1) + r0 + j] * kc;
    }
    #pragma unroll
    for (int j = 0; j < GR / 2; ++j) {
        if (r0 + j < nrows)
            value[(size_t)(rowbase + r0 + j) * D + c] = acc[j];
    }
}

// pass A: e = leaky(adj*sa1[row] + adj*sa2[col]); segment max via atomicMax
__global__ void k_edge_scores(const int* __restrict__ erow,
                              const int* __restrict__ ecol,
                              const float* __restrict__ adj,
                              const float* __restrict__ sa1,
                              const float* __restrict__ sa2,
                              float* __restrict__ e,
                              unsigned* __restrict__ mkey, int ne) {
    int k = blockIdx.x * blockDim.x + threadIdx.x;
    if (k >= ne) return;
    int r = erow[k], c = ecol[k];
    float v = adj[k];
    float s = v * sa1[r] + v * sa2[c];
    s = (s >= 0.f) ? s : ALPHA * s;
    e[k] = s;
    atomicMax(&mkey[r], enc_f32(s));
}

// pass B: ex = exp(e - m[row]); denom[row] += ex  (overwrites e with ex)
__global__ void k_edge_exp(const int* __restrict__ erow,
                           float* __restrict__ e,
                           const unsigned* __restrict__ mkey,
                           float* __restrict__ denom, int ne) {
    int k = blockIdx.x * blockDim.x + threadIdx.x;
    if (k >= ne) return;
    int r = erow[k];
    float ex = __expf(e[k] - dec_f32(mkey[r]));
    e[k] = ex;
    unsafeAtomicAdd(&denom[r], ex);
}

// pass C: out[row] += (ex/denom[row]) * value[col]   (128 threads per edge)
__global__ __launch_bounds__(256) void k_spmm(
        const int* __restrict__ erow, const int* __restrict__ ecol,
        const float* __restrict__ e, const float* __restrict__ denom,
        const float* __restrict__ value, float* __restrict__ out, int ne) {
    int eidx = blockIdx.x * 2 + (threadIdx.x >> 7);
    if (eidx >= ne) return;
    int c = threadIdx.x & 127;
    int r = erow[eidx], col = ecol[eidx];
    float att = e[eidx] / denom[r];
    unsafeAtomicAdd(&out[(size_t)r * D + c], att * value[(size_t)col * D + c]);
}

extern "C" void kernel_launch(void* const* d_in, const int* in_sizes, int n_in,
                              void* d_out, int out_size, void* d_ws, size_t ws_size,
                              hipStream_t stream) {
    const float* x    = (const float*)d_in[0];
    const float* adj  = (const float*)d_in[1];
    const int*   erow = (const int*)d_in[2];
    const int*   ecol = (const int*)d_in[3];
    const float* Wmap = (const float*)d_in[4];
    const float* w1   = (const float*)d_in[5];
    const float* b1   = (const float*)d_in[6];
    const float* w2   = (const float*)d_in[7];
    const float* b2   = (const float*)d_in[8];
    const float* kern = (const float*)d_in[9];
    const float* bias = (const float*)d_in[10];
    float* out = (float*)d_out;

    int n  = in_sizes[0] / D;   // 100000
    int ne = in_sizes[1];       // 1600000

    char* ws = (char*)d_ws;
    size_t off = 0;
    float* value = (float*)(ws + off); off += (size_t)n * D * sizeof(float);
    float* e     = (float*)(ws + off); off += (size_t)ne * sizeof(float);
    float* sa1   = (float*)(ws + off); off += ((size_t)n * sizeof(float) + 255) & ~255ull;
    float* sa2   = (float*)(ws + off); off += ((size_t)n * sizeof(float) + 255) & ~255ull;
    unsigned* mkey = (unsigned*)(ws + off); off += ((size_t)n * sizeof(unsigned) + 255) & ~255ull;
    float* denom = (float*)(ws + off); off += ((size_t)n * sizeof(float) + 255) & ~255ull;
    float* u     = (float*)(ws + off); off += 2 * D * sizeof(float);

    k_compute_u<<<1, D, 0, stream>>>(Wmap, w1, w2, u);
    k_init<<<(n * D + 255) / 256, 256, 0, stream>>>(bias, out, mkey, denom, n);
    k_scores<<<(n + 3) / 4, 256, 0, stream>>>(x, u, b1, b2, sa1, sa2, n);
    k_value_gemm<<<(n + GR - 1) / GR, 256, 0, stream>>>(x, kern, value, n);
    k_edge_scores<<<(ne + 255) / 256, 256, 0, stream>>>(erow, ecol, adj, sa1, sa2, e, mkey, ne);
    k_edge_exp<<<(ne + 255) / 256, 256, 0, stream>>>(erow, e, mkey, denom, ne);
    k_spmm<<<(ne + 1) / 2, 256, 0, stream>>>(erow, ecol, e, denom, value, out, ne);
}

// Round 2
// 420.095 us; speedup vs baseline: 2.3579x; 2.3579x over previous
//
#include <hip/hip_runtime.h>

#define D 128
#define ALPHA 0.2f

// u[0..127] = W_map @ w1 ; u[128..255] = W_map @ w2. One block of 128.
__global__ void k_compute_u(const float* __restrict__ Wmap,
                            const float* __restrict__ w1,
                            const float* __restrict__ w2,
                            float* __restrict__ u) {
    int i = threadIdx.x;
    float s1 = 0.f, s2 = 0.f;
    for (int j = 0; j < D; ++j) {
        float w = Wmap[i * D + j];
        s1 += w * w1[j];
        s2 += w * w2[j];
    }
    u[i] = s1;
    u[D + i] = s2;
}

__global__ void k_zero(unsigned* __restrict__ cnt, unsigned* __restrict__ fill,
                       int* __restrict__ rowptr, int n, int ne) {
    int i = blockIdx.x * blockDim.x + threadIdx.x;
    if (i < n) { cnt[i] = 0u; fill[i] = 0u; }
    if (i == 0) rowptr[n] = ne;
}

__global__ void k_hist(const int* __restrict__ erow, unsigned* __restrict__ cnt, int ne) {
    int k = blockIdx.x * blockDim.x + threadIdx.x;
    if (k < ne) atomicAdd(&cnt[erow[k]], 1u);
}

// per-block sums of cnt
__global__ __launch_bounds__(256) void k_scan1(const unsigned* __restrict__ cnt,
                                               unsigned* __restrict__ bsum, int n) {
    int i = blockIdx.x * 256 + threadIdx.x;
    unsigned v = (i < n) ? cnt[i] : 0u;
    #pragma unroll
    for (int off = 32; off; off >>= 1) v += __shfl_xor(v, off);
    __shared__ unsigned ws_[4];
    if ((threadIdx.x & 63) == 0) ws_[threadIdx.x >> 6] = v;
    __syncthreads();
    if (threadIdx.x == 0) bsum[blockIdx.x] = ws_[0] + ws_[1] + ws_[2] + ws_[3];
}

// exclusive scan of block sums (nb <= 512), one block
__global__ __launch_bounds__(512) void k_scan2(const unsigned* __restrict__ bsum,
                                               unsigned* __restrict__ ebsum, int nb) {
    __shared__ unsigned sh[512];
    int t = threadIdx.x;
    unsigned v = (t < nb) ? bsum[t] : 0u;
    sh[t] = v;
    __syncthreads();
    for (int off = 1; off < 512; off <<= 1) {
        unsigned add = (t >= off) ? sh[t - off] : 0u;
        __syncthreads();
        sh[t] += add;
        __syncthreads();
    }
    if (t < nb) ebsum[t] = sh[t] - v;
}

// rowptr[i] = ebsum[block] + exclusive_scan_within_block(cnt)
__global__ __launch_bounds__(256) void k_scan3(const unsigned* __restrict__ cnt,
                                               const unsigned* __restrict__ ebsum,
                                               int* __restrict__ rowptr, int n) {
    __shared__ unsigned sh[256];
    int i = blockIdx.x * 256 + threadIdx.x;
    int t = threadIdx.x;
    unsigned v = (i < n) ? cnt[i] : 0u;
    sh[t] = v;
    __syncthreads();
    for (int off = 1; off < 256; off <<= 1) {
        unsigned add = (t >= off) ? sh[t - off] : 0u;
        __syncthreads();
        sh[t] += add;
        __syncthreads();
    }
    if (i < n) rowptr[i] = (int)(ebsum[blockIdx.x] + sh[t] - v);
}

__global__ void k_scatter(const int* __restrict__ erow, const int* __restrict__ ecol,
                          const float* __restrict__ adj, const int* __restrict__ rowptr,
                          unsigned* __restrict__ fill, int* __restrict__ csr_col,
                          float* __restrict__ csr_adj, int ne) {
    int k = blockIdx.x * blockDim.x + threadIdx.x;
    if (k >= ne) return;
    int r = erow[k];
    int pos = rowptr[r] + (int)atomicAdd(&fill[r], 1u);
    csr_col[pos] = ecol[k];
    csr_adj[pos] = adj[k];
}

// value = x @ kernel, fused with per-node attention scores:
// sa1[r] = x[r].(W_map@w1) + b1, sa2[r] = x[r].(W_map@w2) + b2
#define GR 64
__global__ __launch_bounds__(256) void k_value_gemm(
        const float* __restrict__ x, const float* __restrict__ kern,
        const float* __restrict__ u, const float* __restrict__ b1,
        const float* __restrict__ b2, float* __restrict__ value,
        float* __restrict__ sa1, float* __restrict__ sa2, int n) {
    __shared__ float Xt[D * (GR + 1)];
    int t = threadIdx.x;
    int rowbase = blockIdx.x * GR;
    int nrows = min(GR, n - rowbase);
    for (int i = t; i < nrows * D; i += 256) {
        int r = i >> 7, k = i & (D - 1);
        Xt[k * (GR + 1) + r] = x[(size_t)(rowbase + r) * D + k];
    }
    __syncthreads();
    // fused scores: threads 0..63 each own one row
    if (t < nrows) {
        float s1 = 0.f, s2 = 0.f;
        for (int k = 0; k < D; ++k) {
            float xv = Xt[k * (GR + 1) + t];
            s1 += xv * u[k];
            s2 += xv * u[D + k];
        }
        sa1[rowbase + t] = s1 + b1[0];
        sa2[rowbase + t] = s2 + b2[0];
    }
    int c = t & 127;
    int r0 = (t >> 7) * (GR / 2);
    float acc[GR / 2];
    #pragma unroll
    for (int j = 0; j < GR / 2; ++j) acc[j] = 0.f;
    for (int k = 0; k < D; ++k) {
        float kc = kern[k * D + c];
        #pragma unroll
        for (int j = 0; j < GR / 2; ++j)
            acc[j] += Xt[k * (GR + 1) + r0 + j] * kc;
    }
    #pragma unroll
    for (int j = 0; j < GR / 2; ++j) {
        if (r0 + j < nrows)
            value[(size_t)(rowbase + r0 + j) * D + c] = acc[j];
    }
}

// one wave per row: fused leaky+softmax+SpMM, no atomics, single coalesced write
__global__ __launch_bounds__(256) void k_row_attn(
        const int* __restrict__ rowptr, const int* __restrict__ csr_col,
        const float* __restrict__ csr_adj, const float* __restrict__ sa1,
        const float* __restrict__ sa2, const float* __restrict__ value,
        const float* __restrict__ bias, float* __restrict__ out, int n) {
    int wid = (blockIdx.x * 256 + threadIdx.x) >> 6;  // row id (wave-uniform)
    int lane = threadIdx.x & 63;
    if (wid >= n) return;
    int start = rowptr[wid], end = rowptr[wid + 1];
    float sa1r = sa1[wid];

    // sweep A: row max of leaky scores (lanes parallel over edges)
    float m = -INFINITY;
    for (int base = start; base < end; base += 64) {
        int k = base + lane;
        if (k < end) {
            int c = csr_col[k];
            float a = csr_adj[k];
            float s = a * sa1r + a * sa2[c];
            s = (s >= 0.f) ? s : ALPHA * s;
            m = fmaxf(m, s);
        }
    }
    #pragma unroll
    for (int off = 32; off; off >>= 1) m = fmaxf(m, __shfl_xor(m, off));

    // sweep B: ex per edge (lane-parallel), then broadcast-serial accumulation
    float2 acc = make_float2(0.f, 0.f);
    float dsum = 0.f;
    for (int base = start; base < end; base += 64) {
        int k = base + lane;
        int cnt = min(64, end - base);
        float ex = 0.f;
        int c = 0;
        if (k < end) {
            c = csr_col[k];
            float a = csr_adj[k];
            float s = a * sa1r + a * sa2[c];
            s = (s >= 0.f) ? s : ALPHA * s;
            ex = __expf(s - m);
            dsum += ex;
        }
        int j = 0;
        for (; j + 2 <= cnt; j += 2) {
            float ex0 = __shfl(ex, j), ex1 = __shfl(ex, j + 1);
            int c0 = __shfl(c, j), c1 = __shfl(c, j + 1);
            float2 v0 = ((const float2*)(value + (size_t)c0 * D))[lane];
            float2 v1 = ((const float2*)(value + (size_t)c1 * D))[lane];
            acc.x += ex0 * v0.x; acc.y += ex0 * v0.y;
            acc.x += ex1 * v1.x; acc.y += ex1 * v1.y;
        }
        if (j < cnt) {
            float ex0 = __shfl(ex, j);
            int c0 = __shfl(c, j);
            float2 v0 = ((const float2*)(value + (size_t)c0 * D))[lane];
            acc.x += ex0 * v0.x; acc.y += ex0 * v0.y;
        }
    }
    #pragma unroll
    for (int off = 32; off; off >>= 1) dsum += __shfl_xor(dsum, off);
    float inv = (dsum > 0.f) ? 1.f / dsum : 0.f;  // empty row -> out = bias

    size_t o = (size_t)wid * D;
    float2 bv = ((const float2*)(bias + o))[lane];
    float2 ov;
    ov.x = acc.x * inv + bv.x;
    ov.y = acc.y * inv + bv.y;
    ((float2*)(out + o))[lane] = ov;
}

extern "C" void kernel_launch(void* const* d_in, const int* in_sizes, int n_in,
                              void* d_out, int out_size, void* d_ws, size_t ws_size,
                              hipStream_t stream) {
    const float* x    = (const float*)d_in[0];
    const float* adj  = (const float*)d_in[1];
    const int*   erow = (const int*)d_in[2];
    const int*   ecol = (const int*)d_in[3];
    const float* Wmap = (const float*)d_in[4];
    const float* w1   = (const float*)d_in[5];
    const float* b1   = (const float*)d_in[6];
    const float* w2   = (const float*)d_in[7];
    const float* b2   = (const float*)d_in[8];
    const float* kern = (const float*)d_in[9];
    const float* bias = (const float*)d_in[10];
    float* out = (float*)d_out;

    int n  = in_sizes[0] / D;   // 100000
    int ne = in_sizes[1];       // 1600000
    int nb = (n + 255) / 256;   // 391 scan blocks

    char* ws = (char*)d_ws;
    size_t off = 0;
    auto alloc = [&](size_t bytes) {
        void* p = ws + off;
        off += (bytes + 255) & ~255ull;
        return p;
    };
    float*    value   = (float*)alloc((size_t)n * D * sizeof(float));
    int*      csr_col = (int*)alloc((size_t)ne * sizeof(int));
    float*    csr_adj = (float*)alloc((size_t)ne * sizeof(float));
    int*      rowptr  = (int*)alloc(((size_t)n + 1) * sizeof(int));
    unsigned* cnt     = (unsigned*)alloc((size_t)n * sizeof(unsigned));
    unsigned* fill    = (unsigned*)alloc((size_t)n * sizeof(unsigned));
    float*    sa1     = (float*)alloc((size_t)n * sizeof(float));
    float*    sa2     = (float*)alloc((size_t)n * sizeof(float));
    unsigned* bsum    = (unsigned*)alloc((size_t)nb * sizeof(unsigned));
    unsigned* ebsum   = (unsigned*)alloc((size_t)nb * sizeof(unsigned));
    float*    u       = (float*)alloc(2 * D * sizeof(float));

    k_compute_u<<<1, D, 0, stream>>>(Wmap, w1, w2, u);
    k_zero<<<(n + 255) / 256, 256, 0, stream>>>(cnt, fill, rowptr, n, ne);
    k_value_gemm<<<(n + GR - 1) / GR, 256, 0, stream>>>(x, kern, u, b1, b2,
                                                        value, sa1, sa2, n);
    k_hist<<<(ne + 255) / 256, 256, 0, stream>>>(erow, cnt, ne);
    k_scan1<<<nb, 256, 0, stream>>>(cnt, bsum, n);
    k_scan2<<<1, 512, 0, stream>>>(bsum, ebsum, nb);
    k_scan3<<<nb, 256, 0, stream>>>(cnt, ebsum, rowptr, n);
    k_scatter<<<(ne + 255) / 256, 256, 0, stream>>>(erow, ecol, adj, rowptr, fill,
                                                    csr_col, csr_adj, ne);
    k_row_attn<<<(n + 3) / 4, 256, 0, stream>>>(rowptr, csr_col, csr_adj,
                                                sa1, sa2, value, bias, out, n);
}

// Round 3
// 377.495 us; speedup vs baseline: 2.6240x; 1.1129x over previous
//
#include <hip/hip_runtime.h>

#define D 128
#define ALPHA 0.2f

__device__ __forceinline__ unsigned short f32_to_bf16(float f) {
    unsigned u = __float_as_uint(f);
    unsigned r = u + 0x7FFFu + ((u >> 16) & 1u);   // round-to-nearest-even
    return (unsigned short)(r >> 16);
}
__device__ __forceinline__ float bf16lo(unsigned u) {
    return __uint_as_float(u << 16);
}
__device__ __forceinline__ float bf16hi(unsigned u) {
    return __uint_as_float(u & 0xFFFF0000u);
}

// u[0..127] = W_map @ w1 ; u[128..255] = W_map @ w2. One block of 128.
__global__ void k_compute_u(const float* __restrict__ Wmap,
                            const float* __restrict__ w1,
                            const float* __restrict__ w2,
                            float* __restrict__ u) {
    int i = threadIdx.x;
    float s1 = 0.f, s2 = 0.f;
    for (int j = 0; j < D; ++j) {
        float w = Wmap[i * D + j];
        s1 += w * w1[j];
        s2 += w * w2[j];
    }
    u[i] = s1;
    u[D + i] = s2;
}

__global__ void k_zero(unsigned* __restrict__ cnt, unsigned* __restrict__ fill,
                       int* __restrict__ rowptr, int n, int ne) {
    int i = blockIdx.x * blockDim.x + threadIdx.x;
    if (i < n) { cnt[i] = 0u; fill[i] = 0u; }
    if (i == 0) rowptr[n] = ne;
}

__global__ void k_hist(const int* __restrict__ erow, unsigned* __restrict__ cnt, int ne) {
    int k = blockIdx.x * blockDim.x + threadIdx.x;
    if (k < ne) atomicAdd(&cnt[erow[k]], 1u);
}

// per-block sums of cnt
__global__ __launch_bounds__(256) void k_scan1(const unsigned* __restrict__ cnt,
                                               unsigned* __restrict__ bsum, int n) {
    int i = blockIdx.x * 256 + threadIdx.x;
    unsigned v = (i < n) ? cnt[i] : 0u;
    #pragma unroll
    for (int off = 32; off; off >>= 1) v += __shfl_xor(v, off);
    __shared__ unsigned ws_[4];
    if ((threadIdx.x & 63) == 0) ws_[threadIdx.x >> 6] = v;
    __syncthreads();
    if (threadIdx.x == 0) bsum[blockIdx.x] = ws_[0] + ws_[1] + ws_[2] + ws_[3];
}

// exclusive scan of block sums (nb <= 512), one block
__global__ __launch_bounds__(512) void k_scan2(const unsigned* __restrict__ bsum,
                                               unsigned* __restrict__ ebsum, int nb) {
    __shared__ unsigned sh[512];
    int t = threadIdx.x;
    unsigned v = (t < nb) ? bsum[t] : 0u;
    sh[t] = v;
    __syncthreads();
    for (int off = 1; off < 512; off <<= 1) {
        unsigned add = (t >= off) ? sh[t - off] : 0u;
        __syncthreads();
        sh[t] += add;
        __syncthreads();
    }
    if (t < nb) ebsum[t] = sh[t] - v;
}

// rowptr[i] = ebsum[block] + exclusive_scan_within_block(cnt)
__global__ __launch_bounds__(256) void k_scan3(const unsigned* __restrict__ cnt,
                                               const unsigned* __restrict__ ebsum,
                                               int* __restrict__ rowptr, int n) {
    __shared__ unsigned sh[256];
    int i = blockIdx.x * 256 + threadIdx.x;
    int t = threadIdx.x;
    unsigned v = (i < n) ? cnt[i] : 0u;
    sh[t] = v;
    __syncthreads();
    for (int off = 1; off < 256; off <<= 1) {
        unsigned add = (t >= off) ? sh[t - off] : 0u;
        __syncthreads();
        sh[t] += add;
        __syncthreads();
    }
    if (i < n) rowptr[i] = (int)(ebsum[blockIdx.x] + sh[t] - v);
}

// scatter edges into CSR order; one 8B store per edge {col, adj_bits}
__global__ void k_scatter(const int* __restrict__ erow, const int* __restrict__ ecol,
                          const float* __restrict__ adj, const int* __restrict__ rowptr,
                          unsigned* __restrict__ fill, int2* __restrict__ csr, int ne) {
    int k = blockIdx.x * blockDim.x + threadIdx.x;
    if (k >= ne) return;
    int r = erow[k];
    int pos = rowptr[r] + (int)atomicAdd(&fill[r], 1u);
    csr[pos] = make_int2(ecol[k], __float_as_int(adj[k]));
}

// value(bf16) = x @ kernel, fused with per-node attention scores
#define GR 64
__global__ __launch_bounds__(256) void k_value_gemm(
        const float* __restrict__ x, const float* __restrict__ kern,
        const float* __restrict__ u, const float* __restrict__ b1,
        const float* __restrict__ b2, unsigned short* __restrict__ valbf,
        float* __restrict__ sa1, float* __restrict__ sa2, int n) {
    __shared__ float Xt[D * (GR + 1)];
    int t = threadIdx.x;
    int rowbase = blockIdx.x * GR;
    int nrows = min(GR, n - rowbase);
    for (int i = t; i < nrows * D; i += 256) {
        int r = i >> 7, k = i & (D - 1);
        Xt[k * (GR + 1) + r] = x[(size_t)(rowbase + r) * D + k];
    }
    __syncthreads();
    if (t < nrows) {
        float s1 = 0.f, s2 = 0.f;
        for (int k = 0; k < D; ++k) {
            float xv = Xt[k * (GR + 1) + t];
            s1 += xv * u[k];
            s2 += xv * u[D + k];
        }
        sa1[rowbase + t] = s1 + b1[0];
        sa2[rowbase + t] = s2 + b2[0];
    }
    int c = t & 127;
    int r0 = (t >> 7) * (GR / 2);
    float acc[GR / 2];
    #pragma unroll
    for (int j = 0; j < GR / 2; ++j) acc[j] = 0.f;
    for (int k = 0; k < D; ++k) {
        float kc = kern[k * D + c];
        #pragma unroll
        for (int j = 0; j < GR / 2; ++j)
            acc[j] += Xt[k * (GR + 1) + r0 + j] * kc;
    }
    #pragma unroll
    for (int j = 0; j < GR / 2; ++j) {
        if (r0 + j < nrows)
            valbf[(size_t)(rowbase + r0 + j) * D + c] = f32_to_bf16(acc[j]);
    }
}

// one wave per row: fused leaky+softmax+SpMM over bf16 value rows.
// Lanes 0-31 / 32-63 process two edges simultaneously (4 in flight per iter).
__global__ __launch_bounds__(256) void k_row_attn(
        const int* __restrict__ rowptr, const int2* __restrict__ csr,
        const float* __restrict__ sa1, const float* __restrict__ sa2,
        const unsigned short* __restrict__ valbf,
        const float* __restrict__ bias, float* __restrict__ out, int n) {
    int wid = (blockIdx.x * 256 + threadIdx.x) >> 6;
    int lane = threadIdx.x & 63;
    if (wid >= n) return;
    int start = rowptr[wid], end = rowptr[wid + 1];
    float sa1r = sa1[wid];

    // sweep A: row max of leaky scores
    float m = -INFINITY;
    for (int base = start; base < end; base += 64) {
        int k = base + lane;
        if (k < end) {
            int2 ca = csr[k];
            float a = __int_as_float(ca.y);
            float s = a * sa1r + a * sa2[ca.x];
            s = (s >= 0.f) ? s : ALPHA * s;
            m = fmaxf(m, s);
        }
    }
    #pragma unroll
    for (int off = 32; off; off >>= 1) m = fmaxf(m, __shfl_xor(m, off));

    // sweep B: ex per edge, half-wave gather of bf16 value rows
    int half = lane >> 5, sub = lane & 31;
    float acc0 = 0.f, acc1 = 0.f, acc2 = 0.f, acc3 = 0.f;
    float dsum = 0.f;
    for (int base = start; base < end; base += 64) {
        int k = base + lane;
        int cnt = min(64, end - base);
        float ex = 0.f;
        int c = 0;
        if (k < end) {
            int2 ca = csr[k];
            c = ca.x;
            float a = __int_as_float(ca.y);
            float s = a * sa1r + a * sa2[c];
            s = (s >= 0.f) ? s : ALPHA * s;
            ex = __expf(s - m);
            dsum += ex;
        }
        for (int j = 0; j < cnt; j += 4) {
            int e0 = j + half, e1 = j + 2 + half;
            float ex0 = __shfl(ex, e0); int c0 = __shfl(c, e0);
            float ex1 = __shfl(ex, e1); int c1 = __shfl(c, e1);
            if (e0 >= cnt) { ex0 = 0.f; c0 = 0; }
            if (e1 >= cnt) { ex1 = 0.f; c1 = 0; }
            uint2 p0 = ((const uint2*)(valbf + (size_t)c0 * D))[sub];
            uint2 p1 = ((const uint2*)(valbf + (size_t)c1 * D))[sub];
            acc0 += ex0 * bf16lo(p0.x); acc1 += ex0 * bf16hi(p0.x);
            acc2 += ex0 * bf16lo(p0.y); acc3 += ex0 * bf16hi(p0.y);
            acc0 += ex1 * bf16lo(p1.x); acc1 += ex1 * bf16hi(p1.x);
            acc2 += ex1 * bf16lo(p1.y); acc3 += ex1 * bf16hi(p1.y);
        }
    }
    acc0 += __shfl_xor(acc0, 32);
    acc1 += __shfl_xor(acc1, 32);
    acc2 += __shfl_xor(acc2, 32);
    acc3 += __shfl_xor(acc3, 32);
    #pragma unroll
    for (int off = 32; off; off >>= 1) dsum += __shfl_xor(dsum, off);
    float inv = (dsum > 0.f) ? 1.f / dsum : 0.f;  // empty row -> out = bias

    if (half == 0) {
        size_t o = (size_t)wid * D + (size_t)sub * 4;
        float4 bv = *(const float4*)(bias + o);
        float4 ov;
        ov.x = acc0 * inv + bv.x;
        ov.y = acc1 * inv + bv.y;
        ov.z = acc2 * inv + bv.z;
        ov.w = acc3 * inv + bv.w;
        *(float4*)(out + o) = ov;
    }
}

extern "C" void kernel_launch(void* const* d_in, const int* in_sizes, int n_in,
                              void* d_out, int out_size, void* d_ws, size_t ws_size,
                              hipStream_t stream) {
    const float* x    = (const float*)d_in[0];
    const float* adj  = (const float*)d_in[1];
    const int*   erow = (const int*)d_in[2];
    const int*   ecol = (const int*)d_in[3];
    const float* Wmap = (const float*)d_in[4];
    const float* w1   = (const float*)d_in[5];
    const float* b1   = (const float*)d_in[6];
    const float* w2   = (const float*)d_in[7];
    const float* b2   = (const float*)d_in[8];
    const float* kern = (const float*)d_in[9];
    const float* bias = (const float*)d_in[10];
    float* out = (float*)d_out;

    int n  = in_sizes[0] / D;   // 100000
    int ne = in_sizes[1];       // 1600000
    int nb = (n + 255) / 256;   // 391 scan blocks

    char* ws = (char*)d_ws;
    size_t off = 0;
    auto alloc = [&](size_t bytes) {
        void* p = ws + off;
        off += (bytes + 255) & ~255ull;
        return p;
    };
    unsigned short* valbf = (unsigned short*)alloc((size_t)n * D * sizeof(unsigned short));
    int2*     csr     = (int2*)alloc((size_t)ne * sizeof(int2));
    int*      rowptr  = (int*)alloc(((size_t)n + 1) * sizeof(int));
    unsigned* cnt     = (unsigned*)alloc((size_t)n * sizeof(unsigned));
    unsigned* fill    = (unsigned*)alloc((size_t)n * sizeof(unsigned));
    float*    sa1     = (float*)alloc((size_t)n * sizeof(float));
    float*    sa2     = (float*)alloc((size_t)n * sizeof(float));
    unsigned* bsum    = (unsigned*)alloc((size_t)nb * sizeof(unsigned));
    unsigned* ebsum   = (unsigned*)alloc((size_t)nb * sizeof(unsigned));
    float*    u       = (float*)alloc(2 * D * sizeof(float));

    k_compute_u<<<1, D, 0, stream>>>(Wmap, w1, w2, u);
    k_zero<<<(n + 255) / 256, 256, 0, stream>>>(cnt, fill, rowptr, n, ne);
    k_value_gemm<<<(n + GR - 1) / GR, 256, 0, stream>>>(x, kern, u, b1, b2,
                                                        valbf, sa1, sa2, n);
    k_hist<<<(ne + 255) / 256, 256, 0, stream>>>(erow, cnt, ne);
    k_scan1<<<nb, 256, 0, stream>>>(cnt, bsum, n);
    k_scan2<<<1, 512, 0, stream>>>(bsum, ebsum, nb);
    k_scan3<<<nb, 256, 0, stream>>>(cnt, ebsum, rowptr, n);
    k_scatter<<<(ne + 255) / 256, 256, 0, stream>>>(erow, ecol, adj, rowptr, fill,
                                                    csr, ne);
    k_row_attn<<<(n + 3) / 4, 256, 0, stream>>>(rowptr, csr, sa1, sa2,
                                                valbf, bias, out, n);
}

// Round 4
// 327.787 us; speedup vs baseline: 3.0219x; 1.1516x over previous
//
#include <hip/hip_runtime.h>

#define D 128
#define ALPHA 0.2f

typedef __attribute__((ext_vector_type(8))) short bf16x8;
typedef __attribute__((ext_vector_type(4))) float f32x4;

__device__ __forceinline__ unsigned short f32_to_bf16(float f) {
    unsigned u = __float_as_uint(f);
    unsigned r = u + 0x7FFFu + ((u >> 16) & 1u);   // round-to-nearest-even
    return (unsigned short)(r >> 16);
}
__device__ __forceinline__ float bf16lo(unsigned u) {
    return __uint_as_float(u << 16);
}
__device__ __forceinline__ float bf16hi(unsigned u) {
    return __uint_as_float(u & 0xFFFF0000u);
}

// Build kTbf[144][128] bf16: rows 0..127 = kernel^T, row 128 = W_map@w1,
// row 129 = W_map@w2, rows 130..143 = 0. One block of 256.
__global__ __launch_bounds__(256) void k_prep(
        const float* __restrict__ Wmap, const float* __restrict__ w1,
        const float* __restrict__ w2, const float* __restrict__ kern,
        unsigned short* __restrict__ kTbf) {
    int t = threadIdx.x;
    int lane = t & 63, wv = t >> 6;
    float w1a = w1[lane], w1b = w1[64 + lane];
    float w2a = w2[lane], w2b = w2[64 + lane];
    for (int r = 0; r < 32; ++r) {
        int row = wv * 32 + r;
        float xa = Wmap[row * D + lane], xb = Wmap[row * D + 64 + lane];
        float s1 = xa * w1a + xb * w1b;
        float s2 = xa * w2a + xb * w2b;
        #pragma unroll
        for (int off = 32; off; off >>= 1) {
            s1 += __shfl_xor(s1, off);
            s2 += __shfl_xor(s2, off);
        }
        if (lane == 0) {
            kTbf[128 * D + row] = f32_to_bf16(s1);
            kTbf[129 * D + row] = f32_to_bf16(s2);
        }
    }
    for (int idx = t; idx < D * D; idx += 256) {      // kernel^T
        int k = idx >> 7, c = idx & 127;
        kTbf[c * D + k] = f32_to_bf16(kern[idx]);
    }
    for (int idx = 130 * D + t; idx < 144 * D; idx += 256) kTbf[idx] = 0;
}

__global__ void k_zero(unsigned* __restrict__ cnt, unsigned* __restrict__ fill,
                       int* __restrict__ rowptr, int n, int ne) {
    int i = blockIdx.x * blockDim.x + threadIdx.x;
    if (i < n) { cnt[i] = 0u; fill[i] = 0u; }
    if (i == 0) rowptr[n] = ne;
}

__global__ void k_hist(const int* __restrict__ erow, unsigned* __restrict__ cnt, int ne) {
    int k = blockIdx.x * blockDim.x + threadIdx.x;
    if (k < ne) atomicAdd(&cnt[erow[k]], 1u);
}

__global__ __launch_bounds__(256) void k_scan1(const unsigned* __restrict__ cnt,
                                               unsigned* __restrict__ bsum, int n) {
    int i = blockIdx.x * 256 + threadIdx.x;
    unsigned v = (i < n) ? cnt[i] : 0u;
    #pragma unroll
    for (int off = 32; off; off >>= 1) v += __shfl_xor(v, off);
    __shared__ unsigned ws_[4];
    if ((threadIdx.x & 63) == 0) ws_[threadIdx.x >> 6] = v;
    __syncthreads();
    if (threadIdx.x == 0) bsum[blockIdx.x] = ws_[0] + ws_[1] + ws_[2] + ws_[3];
}

__global__ __launch_bounds__(512) void k_scan2(const unsigned* __restrict__ bsum,
                                               unsigned* __restrict__ ebsum, int nb) {
    __shared__ unsigned sh[512];
    int t = threadIdx.x;
    unsigned v = (t < nb) ? bsum[t] : 0u;
    sh[t] = v;
    __syncthreads();
    for (int off = 1; off < 512; off <<= 1) {
        unsigned add = (t >= off) ? sh[t - off] : 0u;
        __syncthreads();
        sh[t] += add;
        __syncthreads();
    }
    if (t < nb) ebsum[t] = sh[t] - v;
}

__global__ __launch_bounds__(256) void k_scan3(const unsigned* __restrict__ cnt,
                                               const unsigned* __restrict__ ebsum,
                                               int* __restrict__ rowptr, int n) {
    __shared__ unsigned sh[256];
    int i = blockIdx.x * 256 + threadIdx.x;
    int t = threadIdx.x;
    unsigned v = (i < n) ? cnt[i] : 0u;
    sh[t] = v;
    __syncthreads();
    for (int off = 1; off < 256; off <<= 1) {
        unsigned add = (t >= off) ? sh[t - off] : 0u;
        __syncthreads();
        sh[t] += add;
        __syncthreads();
    }
    if (i < n) rowptr[i] = (int)(ebsum[blockIdx.x] + sh[t] - v);
}

__global__ void k_scatter(const int* __restrict__ erow, const int* __restrict__ ecol,
                          const float* __restrict__ adj, const int* __restrict__ rowptr,
                          unsigned* __restrict__ fill, int2* __restrict__ csr, int ne) {
    int k = blockIdx.x * blockDim.x + threadIdx.x;
    if (k >= ne) return;
    int r = erow[k];
    int pos = rowptr[r] + (int)atomicAdd(&fill[r], 1u);
    csr[pos] = make_int2(ecol[k], __float_as_int(adj[k]));
}

// MFMA value-GEMM: valbf[n][128] = bf16(x @ kernel); 9th col-block computes
// sa1/sa2 (u1,u2 packed as B columns 128,129). 64 rows/block, 4 waves.
#define BM 64
#define NBLK 9
__global__ __launch_bounds__(256) void k_value_gemm(
        const float* __restrict__ x, const unsigned short* __restrict__ kTbf,
        const float* __restrict__ b1, const float* __restrict__ b2,
        unsigned short* __restrict__ valbf,
        float* __restrict__ sa1, float* __restrict__ sa2, int n) {
    __shared__ unsigned short As[BM * D];          // 16 KB, swizzled
    __shared__ unsigned short Bs[NBLK * 16 * D];   // 36 KB, swizzled
    int t = threadIdx.x;
    int rowbase = blockIdx.x * BM;
    // stage A: fp32 x -> bf16, XOR-swizzled rows
    for (int idx = t; idx < BM * 32; idx += 256) {    // float4 chunks
        int r = idx >> 5, k4 = (idx & 31) << 2;
        unsigned v0 = 0, v1 = 0;
        int grow = rowbase + r;
        if (grow < n) {
            float4 f = *(const float4*)(x + (size_t)grow * D + k4);
            v0 = (unsigned)f32_to_bf16(f.x) | ((unsigned)f32_to_bf16(f.y) << 16);
            v1 = (unsigned)f32_to_bf16(f.z) | ((unsigned)f32_to_bf16(f.w) << 16);
        }
        unsigned byte = (unsigned)(r * 256 + k4 * 2) ^ ((unsigned)(r & 7) << 4);
        *(uint2*)((char*)As + byte) = make_uint2(v0, v1);
    }
    // stage B: linear copy with swizzle (kTbf already [col][k])
    for (int idx = t; idx < NBLK * 16 * 32; idx += 256) {  // 8B chunks
        int rowB = idx >> 5;
        uint2 v = ((const uint2*)kTbf)[idx];
        unsigned byte = (unsigned)(idx * 8) ^ ((unsigned)(rowB & 7) << 4);
        *(uint2*)((char*)Bs + byte) = v;
    }
    __syncthreads();

    int w = t >> 6, lane = t & 63;
    int arow = w * 16 + (lane & 15);
    f32x4 acc[NBLK];
    #pragma unroll
    for (int b = 0; b < NBLK; ++b) acc[b] = (f32x4){0.f, 0.f, 0.f, 0.f};
    #pragma unroll
    for (int ks = 0; ks < 4; ++ks) {
        int kk = ks * 32 + (lane >> 4) * 8;
        unsigned abyte = (unsigned)(arow * 256 + kk * 2) ^ ((unsigned)(arow & 7) << 4);
        bf16x8 af = *(const bf16x8*)((const char*)As + abyte);
        #pragma unroll
        for (int cb = 0; cb < NBLK; ++cb) {
            int brow = cb * 16 + (lane & 15);
            unsigned bbyte = (unsigned)(brow * 256 + kk * 2) ^ ((unsigned)(brow & 7) << 4);
            bf16x8 bfr = *(const bf16x8*)((const char*)Bs + bbyte);
            acc[cb] = __builtin_amdgcn_mfma_f32_16x16x32_bf16(af, bfr, acc[cb], 0, 0, 0);
        }
    }
    // C/D layout: col = lane&15, row = (lane>>4)*4 + i  [verified mapping]
    int col = lane & 15;
    int rbase2 = rowbase + w * 16 + (lane >> 4) * 4;
    #pragma unroll
    for (int cb = 0; cb < 8; ++cb) {
        #pragma unroll
        for (int i = 0; i < 4; ++i) {
            int grow = rbase2 + i;
            if (grow < n)
                valbf[(size_t)grow * D + cb * 16 + col] = f32_to_bf16(acc[cb][i]);
        }
    }
    if (col < 2) {   // cb=8: col0 = sa1, col1 = sa2
        float bb = (col == 0) ? b1[0] : b2[0];
        float* dst = (col == 0) ? sa1 : sa2;
        #pragma unroll
        for (int i = 0; i < 4; ++i) {
            int grow = rbase2 + i;
            if (grow < n) dst[grow] = acc[8][i] + bb;
        }
    }
}

// one wave per row: fused leaky+softmax+SpMM over bf16 value rows.
__global__ __launch_bounds__(256) void k_row_attn(
        const int* __restrict__ rowptr, const int2* __restrict__ csr,
        const float* __restrict__ sa1, const float* __restrict__ sa2,
        const unsigned short* __restrict__ valbf,
        const float* __restrict__ bias, float* __restrict__ out, int n) {
    int wid = (blockIdx.x * 256 + threadIdx.x) >> 6;
    int lane = threadIdx.x & 63;
    if (wid >= n) return;
    int start = rowptr[wid], end = rowptr[wid + 1];
    float sa1r = sa1[wid];

    float m = -INFINITY;
    for (int base = start; base < end; base += 64) {
        int k = base + lane;
        if (k < end) {
            int2 ca = csr[k];
            float a = __int_as_float(ca.y);
            float s = a * sa1r + a * sa2[ca.x];
            s = (s >= 0.f) ? s : ALPHA * s;
            m = fmaxf(m, s);
        }
    }
    #pragma unroll
    for (int off = 32; off; off >>= 1) m = fmaxf(m, __shfl_xor(m, off));

    int half = lane >> 5, sub = lane & 31;
    float acc0 = 0.f, acc1 = 0.f, acc2 = 0.f, acc3 = 0.f;
    float dsum = 0.f;
    for (int base = start; base < end; base += 64) {
        int k = base + lane;
        int cnt = min(64, end - base);
        float ex = 0.f;
        int c = 0;
        if (k < end) {
            int2 ca = csr[k];
            c = ca.x;
            float a = __int_as_float(ca.y);
            float s = a * sa1r + a * sa2[c];
            s = (s >= 0.f) ? s : ALPHA * s;
            ex = __expf(s - m);
            dsum += ex;
        }
        for (int j = 0; j < cnt; j += 4) {
            int e0 = j + half, e1 = j + 2 + half;
            float ex0 = __shfl(ex, e0); int c0 = __shfl(c, e0);
            float ex1 = __shfl(ex, e1); int c1 = __shfl(c, e1);
            if (e0 >= cnt) { ex0 = 0.f; c0 = 0; }
            if (e1 >= cnt) { ex1 = 0.f; c1 = 0; }
            uint2 p0 = ((const uint2*)(valbf + (size_t)c0 * D))[sub];
            uint2 p1 = ((const uint2*)(valbf + (size_t)c1 * D))[sub];
            acc0 += ex0 * bf16lo(p0.x); acc1 += ex0 * bf16hi(p0.x);
            acc2 += ex0 * bf16lo(p0.y); acc3 += ex0 * bf16hi(p0.y);
            acc0 += ex1 * bf16lo(p1.x); acc1 += ex1 * bf16hi(p1.x);
            acc2 += ex1 * bf16lo(p1.y); acc3 += ex1 * bf16hi(p1.y);
        }
    }
    acc0 += __shfl_xor(acc0, 32);
    acc1 += __shfl_xor(acc1, 32);
    acc2 += __shfl_xor(acc2, 32);
    acc3 += __shfl_xor(acc3, 32);
    #pragma unroll
    for (int off = 32; off; off >>= 1) dsum += __shfl_xor(dsum, off);
    float inv = (dsum > 0.f) ? 1.f / dsum : 0.f;

    if (half == 0) {
        size_t o = (size_t)wid * D + (size_t)sub * 4;
        float4 bv = *(const float4*)(bias + o);
        float4 ov;
        ov.x = acc0 * inv + bv.x;
        ov.y = acc1 * inv + bv.y;
        ov.z = acc2 * inv + bv.z;
        ov.w = acc3 * inv + bv.w;
        *(float4*)(out + o) = ov;
    }
}

extern "C" void kernel_launch(void* const* d_in, const int* in_sizes, int n_in,
                              void* d_out, int out_size, void* d_ws, size_t ws_size,
                              hipStream_t stream) {
    const float* x    = (const float*)d_in[0];
    const float* adj  = (const float*)d_in[1];
    const int*   erow = (const int*)d_in[2];
    const int*   ecol = (const int*)d_in[3];
    const float* Wmap = (const float*)d_in[4];
    const float* w1   = (const float*)d_in[5];
    const float* b1   = (const float*)d_in[6];
    const float* w2   = (const float*)d_in[7];
    const float* b2   = (const float*)d_in[8];
    const float* kern = (const float*)d_in[9];
    const float* bias = (const float*)d_in[10];
    float* out = (float*)d_out;

    int n  = in_sizes[0] / D;   // 100000
    int ne = in_sizes[1];       // 1600000
    int nb = (n + 255) / 256;

    char* ws = (char*)d_ws;
    size_t off = 0;
    auto alloc = [&](size_t bytes) {
        void* p = ws + off;
        off += (bytes + 255) & ~255ull;
        return p;
    };
    unsigned short* valbf = (unsigned short*)alloc((size_t)n * D * sizeof(unsigned short));
    int2*     csr     = (int2*)alloc((size_t)ne * sizeof(int2));
    int*      rowptr  = (int*)alloc(((size_t)n + 1) * sizeof(int));
    unsigned* cnt     = (unsigned*)alloc((size_t)n * sizeof(unsigned));
    unsigned* fill    = (unsigned*)alloc((size_t)n * sizeof(unsigned));
    float*    sa1     = (float*)alloc((size_t)n * sizeof(float));
    float*    sa2     = (float*)alloc((size_t)n * sizeof(float));
    unsigned* bsum    = (unsigned*)alloc((size_t)nb * sizeof(unsigned));
    unsigned* ebsum   = (unsigned*)alloc((size_t)nb * sizeof(unsigned));
    unsigned short* kTbf = (unsigned short*)alloc((size_t)144 * D * sizeof(unsigned short));

    k_prep<<<1, 256, 0, stream>>>(Wmap, w1, w2, kern, kTbf);
    k_zero<<<(n + 255) / 256, 256, 0, stream>>>(cnt, fill, rowptr, n, ne);
    k_value_gemm<<<(n + BM - 1) / BM, 256, 0, stream>>>(x, kTbf, b1, b2,
                                                        valbf, sa1, sa2, n);
    k_hist<<<(ne + 255) / 256, 256, 0, stream>>>(erow, cnt, ne);
    k_scan1<<<nb, 256, 0, stream>>>(cnt, bsum, n);
    k_scan2<<<1, 512, 0, stream>>>(bsum, ebsum, nb);
    k_scan3<<<nb, 256, 0, stream>>>(cnt, ebsum, rowptr, n);
    k_scatter<<<(ne + 255) / 256, 256, 0, stream>>>(erow, ecol, adj, rowptr, fill,
                                                    csr, ne);
    k_row_attn<<<(n + 3) / 4, 256, 0, stream>>>(rowptr, csr, sa1, sa2,
                                                valbf, bias, out, n);
}

// Round 5
// 272.453 us; speedup vs baseline: 3.6356x; 1.2031x over previous
//
#include <hip/hip_runtime.h>

#define D 128
#define ALPHA 0.2f
#define CH 8192          // edges per chunk for count/binscatter
#define MAXB 512         // >= nbuk (391)

typedef __attribute__((ext_vector_type(8))) short bf16x8;
typedef __attribute__((ext_vector_type(4))) float f32x4;

__device__ __forceinline__ unsigned short f32_to_bf16(float f) {
    unsigned u = __float_as_uint(f);
    unsigned r = u + 0x7FFFu + ((u >> 16) & 1u);   // round-to-nearest-even
    return (unsigned short)(r >> 16);
}
__device__ __forceinline__ float bf16lo(unsigned u) {
    return __uint_as_float(u << 16);
}
__device__ __forceinline__ float bf16hi(unsigned u) {
    return __uint_as_float(u & 0xFFFF0000u);
}

// Build kTbf[144][128] bf16: rows 0..127 = kernel^T, row 128 = W_map@w1,
// row 129 = W_map@w2, rows 130..143 = 0.
__global__ __launch_bounds__(256) void k_prep(
        const float* __restrict__ Wmap, const float* __restrict__ w1,
        const float* __restrict__ w2, const float* __restrict__ kern,
        unsigned short* __restrict__ kTbf) {
    int t = threadIdx.x;
    int lane = t & 63, wv = t >> 6;
    float w1a = w1[lane], w1b = w1[64 + lane];
    float w2a = w2[lane], w2b = w2[64 + lane];
    for (int r = 0; r < 32; ++r) {
        int row = wv * 32 + r;
        float xa = Wmap[row * D + lane], xb = Wmap[row * D + 64 + lane];
        float s1 = xa * w1a + xb * w1b;
        float s2 = xa * w2a + xb * w2b;
        #pragma unroll
        for (int off = 32; off; off >>= 1) {
            s1 += __shfl_xor(s1, off);
            s2 += __shfl_xor(s2, off);
        }
        if (lane == 0) {
            kTbf[128 * D + row] = f32_to_bf16(s1);
            kTbf[129 * D + row] = f32_to_bf16(s2);
        }
    }
    for (int idx = t; idx < D * D; idx += 256) {      // kernel^T
        int k = idx >> 7, c = idx & 127;
        kTbf[c * D + k] = f32_to_bf16(kern[idx]);
    }
    for (int idx = 130 * D + t; idx < 144 * D; idx += 256) kTbf[idx] = 0;
}

// per-(WG,bucket) histogram; bucket = row >> 8
__global__ __launch_bounds__(256) void k_count(
        const int* __restrict__ erow, unsigned* __restrict__ cnt_mat,
        int ne, int nbuk) {
    __shared__ unsigned cl[MAXB];
    int wg = blockIdx.x, t = threadIdx.x;
    for (int i = t; i < nbuk; i += 256) cl[i] = 0u;
    __syncthreads();
    int base = wg * CH;
    int lim = min(CH, ne - base);
    for (int i = t; i < lim; i += 256)
        atomicAdd(&cl[erow[base + i] >> 8], 1u);
    __syncthreads();
    for (int i = t; i < nbuk; i += 256)
        cnt_mat[(size_t)wg * nbuk + i] = cl[i];
}

// single block: bucket bases + per-(wg,bucket) exclusive offsets
__global__ __launch_bounds__(512) void k_scanb(
        const unsigned* __restrict__ cnt_mat, unsigned* __restrict__ off_mat,
        int* __restrict__ bstart, int nw, int nbuk, int ne) {
    __shared__ unsigned tot[512];
    int t = threadIdx.x;
    unsigned s = 0;
    if (t < nbuk)
        for (int w = 0; w < nw; ++w) s += cnt_mat[(size_t)w * nbuk + t];
    tot[t] = s;
    __syncthreads();
    for (int off = 1; off < 512; off <<= 1) {
        unsigned add = (t >= off) ? tot[t - off] : 0u;
        __syncthreads();
        tot[t] += add;
        __syncthreads();
    }
    unsigned base = tot[t] - s;  // exclusive
    if (t < nbuk) {
        bstart[t] = (int)base;
        unsigned run = base;
        for (int w = 0; w < nw; ++w) {
            off_mat[(size_t)w * nbuk + t] = run;
            run += cnt_mat[(size_t)w * nbuk + t];
        }
    }
    if (t == 0) bstart[nbuk] = ne;
}

// append {row, col, adj_bits} records into per-(WG,bucket) segments
__global__ __launch_bounds__(256) void k_binscatter(
        const int* __restrict__ erow, const int* __restrict__ ecol,
        const float* __restrict__ adj, const unsigned* __restrict__ off_mat,
        int4* __restrict__ recs, int ne, int nbuk) {
    __shared__ unsigned cur[MAXB];
    int wg = blockIdx.x, t = threadIdx.x;
    for (int i = t; i < nbuk; i += 256)
        cur[i] = off_mat[(size_t)wg * nbuk + i];
    __syncthreads();
    int base = wg * CH;
    int lim = min(CH, ne - base);
    for (int i = t; i < lim; i += 256) {
        int k = base + i;
        int r = erow[k];
        unsigned pos = atomicAdd(&cur[r >> 8], 1u);
        recs[pos] = make_int4(r, ecol[k], __float_as_int(adj[k]), 0);
    }
}

// WG per bucket: per-row counts+scan in LDS -> rowptr; scatter {col,adj} into
// the bucket's contiguous CSR window (single-XCD L2-resident writes).
__global__ __launch_bounds__(256) void k_bucket(
        const int4* __restrict__ recs, const int* __restrict__ bstart,
        int* __restrict__ rowptr, int2* __restrict__ csr, int n, int ne) {
    __shared__ unsigned cntL[256], startL[256], fillL[256];
    int b = blockIdx.x, t = threadIdx.x;
    int rb0 = b << 8;
    int s = bstart[b], e = bstart[b + 1];
    cntL[t] = 0u;
    fillL[t] = 0u;
    __syncthreads();
    for (int i = s + t; i < e; i += 256)
        atomicAdd(&cntL[recs[i].x - rb0], 1u);
    __syncthreads();
    unsigned v = cntL[t];
    startL[t] = v;
    __syncthreads();
    for (int off = 1; off < 256; off <<= 1) {
        unsigned add = (t >= off) ? startL[t - off] : 0u;
        __syncthreads();
        startL[t] += add;
        __syncthreads();
    }
    unsigned myStart = startL[t] - v;  // exclusive within bucket
    startL[t] = myStart;
    if (rb0 + t < n) rowptr[rb0 + t] = s + (int)myStart;
    if (b == 0 && t == 0) rowptr[n] = ne;
    __syncthreads();
    for (int i = s + t; i < e; i += 256) {
        int4 rc = recs[i];
        int r = rc.x - rb0;
        unsigned p = atomicAdd(&fillL[r], 1u);
        csr[s + (int)startL[r] + (int)p] = make_int2(rc.y, rc.z);
    }
}

// MFMA value-GEMM: valbf[n][128] = bf16(x @ kernel); 9th col-block computes
// sa1/sa2 (u1,u2 packed as B columns 128,129). 64 rows/block, 4 waves.
#define BM 64
#define NBLK 9
__global__ __launch_bounds__(256) void k_value_gemm(
        const float* __restrict__ x, const unsigned short* __restrict__ kTbf,
        const float* __restrict__ b1, const float* __restrict__ b2,
        unsigned short* __restrict__ valbf,
        float* __restrict__ sa1, float* __restrict__ sa2, int n) {
    __shared__ unsigned short As[BM * D];          // 16 KB, swizzled
    __shared__ unsigned short Bs[NBLK * 16 * D];   // 36 KB, swizzled
    int t = threadIdx.x;
    int rowbase = blockIdx.x * BM;
    for (int idx = t; idx < BM * 32; idx += 256) {    // float4 chunks
        int r = idx >> 5, k4 = (idx & 31) << 2;
        unsigned v0 = 0, v1 = 0;
        int grow = rowbase + r;
        if (grow < n) {
            float4 f = *(const float4*)(x + (size_t)grow * D + k4);
            v0 = (unsigned)f32_to_bf16(f.x) | ((unsigned)f32_to_bf16(f.y) << 16);
            v1 = (unsigned)f32_to_bf16(f.z) | ((unsigned)f32_to_bf16(f.w) << 16);
        }
        unsigned byte = (unsigned)(r * 256 + k4 * 2) ^ ((unsigned)(r & 7) << 4);
        *(uint2*)((char*)As + byte) = make_uint2(v0, v1);
    }
    for (int idx = t; idx < NBLK * 16 * 32; idx += 256) {  // 8B chunks
        int rowB = idx >> 5;
        uint2 v = ((const uint2*)kTbf)[idx];
        unsigned byte = (unsigned)(idx * 8) ^ ((unsigned)(rowB & 7) << 4);
        *(uint2*)((char*)Bs + byte) = v;
    }
    __syncthreads();

    int w = t >> 6, lane = t & 63;
    int arow = w * 16 + (lane & 15);
    f32x4 acc[NBLK];
    #pragma unroll
    for (int b = 0; b < NBLK; ++b) acc[b] = (f32x4){0.f, 0.f, 0.f, 0.f};
    #pragma unroll
    for (int ks = 0; ks < 4; ++ks) {
        int kk = ks * 32 + (lane >> 4) * 8;
        unsigned abyte = (unsigned)(arow * 256 + kk * 2) ^ ((unsigned)(arow & 7) << 4);
        bf16x8 af = *(const bf16x8*)((const char*)As + abyte);
        #pragma unroll
        for (int cb = 0; cb < NBLK; ++cb) {
            int brow = cb * 16 + (lane & 15);
            unsigned bbyte = (unsigned)(brow * 256 + kk * 2) ^ ((unsigned)(brow & 7) << 4);
            bf16x8 bfr = *(const bf16x8*)((const char*)Bs + bbyte);
            acc[cb] = __builtin_amdgcn_mfma_f32_16x16x32_bf16(af, bfr, acc[cb], 0, 0, 0);
        }
    }
    int col = lane & 15;
    int rbase2 = rowbase + w * 16 + (lane >> 4) * 4;
    #pragma unroll
    for (int cb = 0; cb < 8; ++cb) {
        #pragma unroll
        for (int i = 0; i < 4; ++i) {
            int grow = rbase2 + i;
            if (grow < n)
                valbf[(size_t)grow * D + cb * 16 + col] = f32_to_bf16(acc[cb][i]);
        }
    }
    if (col < 2) {   // cb=8: col0 = sa1, col1 = sa2
        float bb = (col == 0) ? b1[0] : b2[0];
        float* dst = (col == 0) ? sa1 : sa2;
        #pragma unroll
        for (int i = 0; i < 4; ++i) {
            int grow = rbase2 + i;
            if (grow < n) dst[grow] = acc[8][i] + bb;
        }
    }
}

// one wave per row: fused leaky+softmax+SpMM over bf16 value rows.
__global__ __launch_bounds__(256) void k_row_attn(
        const int* __restrict__ rowptr, const int2* __restrict__ csr,
        const float* __restrict__ sa1, const float* __restrict__ sa2,
        const unsigned short* __restrict__ valbf,
        const float* __restrict__ bias, float* __restrict__ out, int n) {
    int wid = (blockIdx.x * 256 + threadIdx.x) >> 6;
    int lane = threadIdx.x & 63;
    if (wid >= n) return;
    int start = rowptr[wid], end = rowptr[wid + 1];
    float sa1r = sa1[wid];

    float m = -INFINITY;
    for (int base = start; base < end; base += 64) {
        int k = base + lane;
        if (k < end) {
            int2 ca = csr[k];
            float a = __int_as_float(ca.y);
            float s = a * sa1r + a * sa2[ca.x];
            s = (s >= 0.f) ? s : ALPHA * s;
            m = fmaxf(m, s);
        }
    }
    #pragma unroll
    for (int off = 32; off; off >>= 1) m = fmaxf(m, __shfl_xor(m, off));

    int half = lane >> 5, sub = lane & 31;
    float acc0 = 0.f, acc1 = 0.f, acc2 = 0.f, acc3 = 0.f;
    float dsum = 0.f;
    for (int base = start; base < end; base += 64) {
        int k = base + lane;
        int cnt = min(64, end - base);
        float ex = 0.f;
        int c = 0;
        if (k < end) {
            int2 ca = csr[k];
            c = ca.x;
            float a = __int_as_float(ca.y);
            float s = a * sa1r + a * sa2[c];
            s = (s >= 0.f) ? s : ALPHA * s;
            ex = __expf(s - m);
            dsum += ex;
        }
        for (int j = 0; j < cnt; j += 4) {
            int e0 = j + half, e1 = j + 2 + half;
            float ex0 = __shfl(ex, e0); int c0 = __shfl(c, e0);
            float ex1 = __shfl(ex, e1); int c1 = __shfl(c, e1);
            if (e0 >= cnt) { ex0 = 0.f; c0 = 0; }
            if (e1 >= cnt) { ex1 = 0.f; c1 = 0; }
            uint2 p0 = ((const uint2*)(valbf + (size_t)c0 * D))[sub];
            uint2 p1 = ((const uint2*)(valbf + (size_t)c1 * D))[sub];
            acc0 += ex0 * bf16lo(p0.x); acc1 += ex0 * bf16hi(p0.x);
            acc2 += ex0 * bf16lo(p0.y); acc3 += ex0 * bf16hi(p0.y);
            acc0 += ex1 * bf16lo(p1.x); acc1 += ex1 * bf16hi(p1.x);
            acc2 += ex1 * bf16lo(p1.y); acc3 += ex1 * bf16hi(p1.y);
        }
    }
    acc0 += __shfl_xor(acc0, 32);
    acc1 += __shfl_xor(acc1, 32);
    acc2 += __shfl_xor(acc2, 32);
    acc3 += __shfl_xor(acc3, 32);
    #pragma unroll
    for (int off = 32; off; off >>= 1) dsum += __shfl_xor(dsum, off);
    float inv = (dsum > 0.f) ? 1.f / dsum : 0.f;

    if (half == 0) {
        size_t o = (size_t)wid * D + (size_t)sub * 4;
        float4 bv = *(const float4*)(bias + o);
        float4 ov;
        ov.x = acc0 * inv + bv.x;
        ov.y = acc1 * inv + bv.y;
        ov.z = acc2 * inv + bv.z;
        ov.w = acc3 * inv + bv.w;
        *(float4*)(out + o) = ov;
    }
}

extern "C" void kernel_launch(void* const* d_in, const int* in_sizes, int n_in,
                              void* d_out, int out_size, void* d_ws, size_t ws_size,
                              hipStream_t stream) {
    const float* x    = (const float*)d_in[0];
    const float* adj  = (const float*)d_in[1];
    const int*   erow = (const int*)d_in[2];
    const int*   ecol = (const int*)d_in[3];
    const float* Wmap = (const float*)d_in[4];
    const float* w1   = (const float*)d_in[5];
    const float* b1   = (const float*)d_in[6];
    const float* w2   = (const float*)d_in[7];
    const float* b2   = (const float*)d_in[8];
    const float* kern = (const float*)d_in[9];
    const float* bias = (const float*)d_in[10];
    float* out = (float*)d_out;

    int n  = in_sizes[0] / D;        // 100000
    int ne = in_sizes[1];            // 1600000
    int nbuk = (n + 255) >> 8;       // 391
    int nw = (ne + CH - 1) / CH;     // 196

    char* ws = (char*)d_ws;
    size_t off = 0;
    auto alloc = [&](size_t bytes) {
        void* p = ws + off;
        off += (bytes + 255) & ~255ull;
        return p;
    };
    // recs (int4 per edge, 25.6MB) aliases valbf (bf16 n*128, 25.6MB):
    // recs is dead once k_bucket completes; k_value_gemm runs after it.
    unsigned short* valbf = (unsigned short*)alloc((size_t)n * D * sizeof(unsigned short));
    int4*     recs    = (int4*)valbf;
    int2*     csr     = (int2*)alloc((size_t)ne * sizeof(int2));
    int*      rowptr  = (int*)alloc(((size_t)n + 1) * sizeof(int));
    int*      bstart  = (int*)alloc(((size_t)nbuk + 1) * sizeof(int));
    unsigned* cnt_mat = (unsigned*)alloc((size_t)nw * nbuk * sizeof(unsigned));
    unsigned* off_mat = (unsigned*)alloc((size_t)nw * nbuk * sizeof(unsigned));
    float*    sa1     = (float*)alloc((size_t)n * sizeof(float));
    float*    sa2     = (float*)alloc((size_t)n * sizeof(float));
    unsigned short* kTbf = (unsigned short*)alloc((size_t)144 * D * sizeof(unsigned short));

    k_prep<<<1, 256, 0, stream>>>(Wmap, w1, w2, kern, kTbf);
    k_count<<<nw, 256, 0, stream>>>(erow, cnt_mat, ne, nbuk);
    k_scanb<<<1, 512, 0, stream>>>(cnt_mat, off_mat, bstart, nw, nbuk, ne);
    k_binscatter<<<nw, 256, 0, stream>>>(erow, ecol, adj, off_mat, recs, ne, nbuk);
    k_bucket<<<nbuk, 256, 0, stream>>>(recs, bstart, rowptr, csr, n, ne);
    k_value_gemm<<<(n + BM - 1) / BM, 256, 0, stream>>>(x, kTbf, b1, b2,
                                                        valbf, sa1, sa2, n);
    k_row_attn<<<(n + 3) / 4, 256, 0, stream>>>(rowptr, csr, sa1, sa2,
                                                valbf, bias, out, n);
}